// Round 3
// baseline (241.985 us; speedup 1.0000x reference)
//
#include <hip/hip_runtime.h>
#include <math.h>

// x: (4, 8192, 1024) f32. _mod_step is an exact identity, so the problem is:
//   h = sigmoid(x·halt_w + halt_b) per token; 3-step ACT recurrence -> (P, n)
//   out = P * x ; ponder = 0.01 * mean(n)
//
// Structure: one wave = one group of 4 tokens, held entirely in registers.
// All 16 global loads issue back-to-back (16 KB in flight per wave), the
// 64-lane butterfly is batched 4-wide (independent shuffles -> ILP on the DS
// chain), and ALL stores happen at the end so the wave never waits on its own
// stores. No atomics: per-block n-sums go to d_ws, reduced by a tiny kernel.
#define N_TOKENS 32768   // 4 * 8192
#define DIM      1024
#define WPB 4            // waves per block
#define TPW 4            // tokens per wave (one register-resident group)
#define NBLOCKS (N_TOKENS / (WPB * TPW))   // 2048

typedef float v4f __attribute__((ext_vector_type(4)));

__global__ __launch_bounds__(256, 4) void modgpt_main(
        const float* __restrict__ x,
        const float* __restrict__ halt_w,
        const float* __restrict__ halt_b,
        float* __restrict__ out,
        int* __restrict__ block_n) {
    const int wave = threadIdx.x >> 6;
    const int lane = threadIdx.x & 63;
    const int token0 = (blockIdx.x * WPB + wave) * TPW;

    const v4f* __restrict__ xin = (const v4f*)(x + (size_t)token0 * DIM);
    v4f* __restrict__ oout      = (v4f*)(out + (size_t)token0 * DIM);
    const v4f* __restrict__ w4  = (const v4f*)halt_w;

    // 16 loads, no intervening dependent math: maximal per-wave MLP.
    v4f xt[TPW][4];
    #pragma unroll
    for (int t = 0; t < TPW; ++t)
        #pragma unroll
        for (int r = 0; r < 4; ++r)
            xt[t][r] = xin[(size_t)t * 256 + lane + r * 64];

    const v4f w0 = w4[lane];
    const v4f w1 = w4[lane + 64];
    const v4f w2 = w4[lane + 128];
    const v4f w3 = w4[lane + 192];
    const float hb = halt_b[0];

    // 4 independent per-lane partial dots
    float d0, d1, d2, d3;
    {
        v4f m;
        m = xt[0][0] * w0 + xt[0][1] * w1 + xt[0][2] * w2 + xt[0][3] * w3;
        d0 = m.x + m.y + m.z + m.w;
        m = xt[1][0] * w0 + xt[1][1] * w1 + xt[1][2] * w2 + xt[1][3] * w3;
        d1 = m.x + m.y + m.z + m.w;
        m = xt[2][0] * w0 + xt[2][1] * w1 + xt[2][2] * w2 + xt[2][3] * w3;
        d2 = m.x + m.y + m.z + m.w;
        m = xt[3][0] * w0 + xt[3][1] * w1 + xt[3][2] * w2 + xt[3][3] * w3;
        d3 = m.x + m.y + m.z + m.w;
    }

    // batched 64-lane butterfly: each step is 4 independent shuffles (ILP=4)
    #pragma unroll
    for (int off = 32; off >= 1; off >>= 1) {
        d0 += __shfl_xor(d0, off, 64);
        d1 += __shfl_xor(d1, off, 64);
        d2 += __shfl_xor(d2, off, 64);
        d3 += __shfl_xor(d3, off, 64);
    }

    // uniform (lane-redundant) ACT recurrence, EPS = 0.01
    float P[TPW];
    int n_sum = 0;
    float dd[TPW] = {d0, d1, d2, d3};
    #pragma unroll
    for (int t = 0; t < TPW; ++t) {
        const float h = 1.0f / (1.0f + expf(-(dd[t] + hb)));
        float acc = 0.0f, rem = 1.0f, Pt = 0.0f;
        #pragma unroll
        for (int s = 0; s < 3; ++s) {
            if (acc < 0.99f) {
                const float na = acc + h;
                const float p  = (na > 0.99f) ? rem : h;
                Pt  += p;
                acc += p;
                rem -= p;
                n_sum += 1;
            }
        }
        P[t] = Pt;
    }

    // all stores at the end: wave retires without waiting on store completion
    #pragma unroll
    for (int t = 0; t < TPW; ++t)
        #pragma unroll
        for (int r = 0; r < 4; ++r)
            oout[(size_t)t * 256 + lane + r * 64] = xt[t][r] * P[t];

    // n_sum is wave-uniform; combine 4 waves via LDS, no global atomics
    __shared__ int sn[WPB];
    if (lane == 0) sn[wave] = n_sum;
    __syncthreads();
    if (threadIdx.x == 0)
        block_n[blockIdx.x] = sn[0] + sn[1] + sn[2] + sn[3];
}

__global__ __launch_bounds__(256) void modgpt_finalize(
        const int* __restrict__ block_n,
        float* __restrict__ ponder_out) {
    __shared__ int ssum[4];
    int v = 0;
    #pragma unroll
    for (int i = 0; i < NBLOCKS / 256; ++i)
        v += block_n[threadIdx.x + i * 256];
    #pragma unroll
    for (int off = 32; off >= 1; off >>= 1)
        v += __shfl_xor(v, off, 64);
    const int wave = threadIdx.x >> 6;
    if ((threadIdx.x & 63) == 0) ssum[wave] = v;
    __syncthreads();
    if (threadIdx.x == 0)
        ponder_out[0] = 0.01f * ((float)(ssum[0] + ssum[1] + ssum[2] + ssum[3])
                                 / (float)N_TOKENS);
}

extern "C" void kernel_launch(void* const* d_in, const int* in_sizes, int n_in,
                              void* d_out, int out_size, void* d_ws, size_t ws_size,
                              hipStream_t stream) {
    const float* x        = (const float*)d_in[0];
    // d_in[1] = router_w : mathematically unused (mod step is identity)
    const float* halt_w   = (const float*)d_in[2];
    const float* halt_b   = (const float*)d_in[3];
    float* out            = (float*)d_out;
    int*   block_n        = (int*)d_ws;

    modgpt_main<<<NBLOCKS, 256, 0, stream>>>(x, halt_w, halt_b, out, block_n);
    modgpt_finalize<<<1, 256, 0, stream>>>(block_n, out + (size_t)N_TOKENS * DIM);
}